// Round 6
// baseline (251.721 us; speedup 1.0000x reference)
//
#include <hip/hip_runtime.h>

// Problem constants (fixed by setup_inputs)
constexpr int H_  = 32;
constexpr int N_  = 256;
constexpr int BS_ = 32;
constexpr int W_  = 128;
constexpr int T_  = 4096;
constexpr int D_  = 128;
constexpr int NQ_ = 8192;          // N_*BS_
constexpr float SCALE_  = 0.08838834764831845f;  // 1/sqrt(128)
constexpr float L2E_    = 1.4426950408889634f;
constexpr float MFLOOR_ = -1.0e28f;
constexpr float DEFER_  = 8.0f;                  // defer-max threshold (T13)

typedef __attribute__((ext_vector_type(4))) float f4;
typedef __attribute__((ext_vector_type(4))) short s4;
typedef __attribute__((ext_vector_type(8))) short s8;
typedef __attribute__((ext_vector_type(4))) float fx4;
typedef __attribute__((ext_vector_type(2))) int i2;

// one v_cvt_pk_bf16_f32: D.lo = bf16(a), D.hi = bf16(b)  (RNE)
__device__ __forceinline__ int pack2(float a, float b) {
  int r;
  asm("v_cvt_pk_bf16_f32 %0, %1, %2" : "=v"(r) : "v"(a), "v"(b));
  return r;
}

union frag_u { int w[4]; s8 v; };

__global__ __launch_bounds__(64, 3)
void mtp_attn_kernel(const float* __restrict__ q,
                     const float* __restrict__ k_ctx,
                     const float* __restrict__ v_ctx,
                     const float* __restrict__ k_draft,
                     const float* __restrict__ v_draft,
                     const int* __restrict__ anchor,
                     const int* __restrict__ keepm,
                     float* __restrict__ out)
{
  // 16384 one-wave blocks. XCD-chunked swizzle (16384 % 8 == 0 -> bijective):
  // each XCD gets a contiguous (unit, wu) range -> 4 heads x all n per XCD.
  int b = blockIdx.x;
  int u = (b & 7) * 2048 + (b >> 3);
  const int wu   = u & 1;        // q-half: queries wu*16..+15
  const int unit = u >> 1;
  const int h = unit >> 8;
  const int n = unit & 255;

  const int lane = threadIdx.x;  // 0..63, single wave, fully independent
  const int l15  = lane & 15;
  const int g    = lane >> 4;    // 0..3

  const int A  = anchor[n];
  const int kp = keepm[n];
  const int wm = W_ - A;         // ctx key valid iff global key idx >= wm

  // Wave-private LDS: K chunk bf16 [16][132] (4224B) + V^T bf16 [128][20] (5120B)
  __shared__ __align__(16) unsigned char smem_[9344];
  short* kb = (short*)smem_;
  short* vT = (short*)(smem_ + 4224);

  // ---- Q B-fragments (bf16 via cvt_pk), kept in registers ----
  const float* qrow = q + ((size_t)h * NQ_ + (size_t)n * BS_ + wu * 16 + l15) * D_;
  s8 qb[4];
#pragma unroll
  for (int ks = 0; ks < 4; ++ks) {
    f4 f0 = *reinterpret_cast<const f4*>(qrow + ks * 32 + g * 4);
    f4 f1 = *reinterpret_cast<const f4*>(qrow + ks * 32 + 16 + g * 4);
    frag_u uq;
    uq.w[0] = pack2(f0[0], f0[1]); uq.w[1] = pack2(f0[2], f0[3]);
    uq.w[2] = pack2(f1[0], f1[1]); uq.w[3] = pack2(f1[2], f1[3]);
    qb[ks] = uq.v;
  }

  // global source bases
  const float* kcb = k_ctx + (size_t)h * T_ * D_;
  const float* vcb = v_ctx + (size_t)h * T_ * D_;
  const float* kdb = k_draft + ((size_t)h * NQ_ + (size_t)n * BS_) * D_;
  const float* vdb = v_draft + ((size_t)h * NQ_ + (size_t)n * BS_) * D_;

  // 16-key chunks, 10 chunks total (0..7 ctx, 8..9 draft)
  f4 kr[8], vr[8];

  auto loadK = [&](int c) {      // K row = l15; f4-cols g + 4i
    const float* src;
    if (c < 8) { int idx = A - W_ + c * 16 + l15; idx = idx < 0 ? 0 : idx; src = kcb + (size_t)idx * D_; }
    else       { src = kdb + (size_t)((c - 8) * 16 + l15) * D_; }
#pragma unroll
    for (int i = 0; i < 8; ++i) kr[i] = reinterpret_cast<const f4*>(src)[g + 4 * i];
  };
  auto loadV = [&](int c) {      // keys g*4+t; f4-cols l15 and l15+16
#pragma unroll
    for (int t = 0; t < 4; ++t) {
      const float* src;
      if (c < 8) { int idx = A - W_ + c * 16 + g * 4 + t; idx = idx < 0 ? 0 : idx; src = vcb + (size_t)idx * D_; }
      else       { src = vdb + (size_t)((c - 8) * 16 + g * 4 + t) * D_; }
      vr[t]     = reinterpret_cast<const f4*>(src)[l15];
      vr[4 + t] = reinterpret_cast<const f4*>(src)[l15 + 16];
    }
  };

  loadK(0); loadV(0);

  float m  = -3.0e38f;
  float ls = 0.0f;
  fx4 oacc[8];
#pragma unroll
  for (int t = 0; t < 8; ++t) oacc[t] = {0.f, 0.f, 0.f, 0.f};

#pragma unroll
  for (int c = 0; c < 10; ++c) {
    // ---- stage chunk c into private LDS (bf16 via cvt_pk); no barriers ----
#pragma unroll
    for (int i = 0; i < 8; ++i) {
      i2 w = { pack2(kr[i][0], kr[i][1]), pack2(kr[i][2], kr[i][3]) };
      *reinterpret_cast<i2*>(kb + l15 * 132 + (g + 4 * i) * 4) = w;
    }
    if (c < 9) loadK(c + 1);     // reissue kr (short WAR wait on the ds_writes)
#pragma unroll
    for (int cc2 = 0; cc2 < 2; ++cc2)
#pragma unroll
      for (int j = 0; j < 4; ++j) {          // 4x4 transpose -> vT[d][key]
        int d = (l15 + 16 * cc2) * 4 + j;
        i2 w = { pack2(vr[cc2 * 4 + 0][j], vr[cc2 * 4 + 1][j]),
                 pack2(vr[cc2 * 4 + 2][j], vr[cc2 * 4 + 3][j]) };
        *reinterpret_cast<i2*>(vT + d * 20 + g * 4) = w;
      }
    if (c < 9) loadV(c + 1);     // reissue vr

    // ---- QK^T swapped: st = mfma(K, Q) -> C[key = g*4+r][q = l15] ----
    fx4 st = {0.f, 0.f, 0.f, 0.f};
    __builtin_amdgcn_s_setprio(1);
#pragma unroll
    for (int ks = 0; ks < 4; ++ks) {
      const short* kpr = kb + l15 * 132 + ks * 32 + g * 4;
      s4 b0 = *reinterpret_cast<const s4*>(kpr);
      s4 b1 = *reinterpret_cast<const s4*>(kpr + 16);
      s8 kf = { b0[0], b0[1], b0[2], b0[3], b1[0], b1[1], b1[2], b1[3] };
      st = __builtin_amdgcn_mfma_f32_16x16x32_bf16(kf, qb[ks], st, 0, 0, 0);
    }
    __builtin_amdgcn_s_setprio(0);

    // ---- mask + scale + chunk max (per query q = l15) ----
    float sv[4];
    float cm = -3.0e38f;
    int kb0 = c * 16 + g * 4;
#pragma unroll
    for (int r = 0; r < 4; ++r) {
      float v = st[r] * SCALE_;
      bool valid = (c >= 8) || (kb0 + r >= wm);
      v = valid ? v : -1.0e30f;
      sv[r] = v;
      cm = fmaxf(cm, v);
    }
    cm = fmaxf(cm, __shfl_xor(cm, 16));
    cm = fmaxf(cm, __shfl_xor(cm, 32));

    // ---- online max with defer threshold ----
    if (c == 0) {
      m = fmaxf(cm, MFLOOR_);
    } else {
      float pm = fmaxf(m, cm);
      if (!__all(pm - m <= DEFER_)) {
        float mn = fmaxf(pm, MFLOOR_);
        float al = exp2f((m - mn) * L2E_);
        ls *= al;
        float alr[4];
#pragma unroll
        for (int r = 0; r < 4; ++r) alr[r] = __shfl(al, g * 4 + r);
#pragma unroll
        for (int nt = 0; nt < 8; ++nt)
#pragma unroll
          for (int r = 0; r < 4; ++r) oacc[nt][r] *= alr[r];
        m = mn;
      }
    }

    // ---- p = exp, accumulate l; PV A-frag = {p0..p3, 0,0,0,0} (exact) ----
    float pv[4];
#pragma unroll
    for (int r = 0; r < 4; ++r) {
      float p = exp2f((sv[r] - m) * L2E_);
      ls += p;
      pv[r] = p;
    }
    frag_u up;
    up.w[0] = pack2(pv[0], pv[1]); up.w[1] = pack2(pv[2], pv[3]);
    up.w[2] = 0; up.w[3] = 0;
    s8 pa = up.v;

    // ---- PV: O[q = g*4+r][d] += P * V (upper-half A is zero -> exact) ----
    __builtin_amdgcn_s_setprio(1);
#pragma unroll
    for (int nt = 0; nt < 8; ++nt) {
      s4 b0 = *reinterpret_cast<const s4*>(vT + (nt * 16 + l15) * 20 + g * 4);
      s8 vb2 = { b0[0], b0[1], b0[2], b0[3], b0[0], b0[1], b0[2], b0[3] };
      oacc[nt] = __builtin_amdgcn_mfma_f32_16x16x32_bf16(pa, vb2, oacc[nt], 0, 0, 0);
    }
    __builtin_amdgcn_s_setprio(0);
  }

  // ---- epilogue: reduce l, redistribute, normalize, store ----
  ls += __shfl_xor(ls, 16);
  ls += __shfl_xor(ls, 32);
  float linv[4];
#pragma unroll
  for (int r = 0; r < 4; ++r) {
    float lq = __shfl(ls, g * 4 + r);
    linv[r] = kp ? (1.0f / lq) : 0.0f;
  }
  float* ob = out + ((size_t)h * NQ_ + (size_t)n * BS_ + wu * 16 + g * 4) * D_ + l15;
#pragma unroll
  for (int nt = 0; nt < 8; ++nt)
#pragma unroll
    for (int r = 0; r < 4; ++r)
      ob[(size_t)r * D_ + nt * 16] = oacc[nt][r] * linv[r];
}

extern "C" void kernel_launch(void* const* d_in, const int* in_sizes, int n_in,
                              void* d_out, int out_size, void* d_ws, size_t ws_size,
                              hipStream_t stream) {
  (void)in_sizes; (void)n_in; (void)d_ws; (void)ws_size; (void)out_size;
  const float* q       = (const float*)d_in[0];
  const float* k_ctx   = (const float*)d_in[1];
  const float* v_ctx   = (const float*)d_in[2];
  const float* k_draft = (const float*)d_in[3];
  const float* v_draft = (const float*)d_in[4];
  const int*   anchor  = (const int*)d_in[5];
  const int*   keep    = (const int*)d_in[6];
  float*       out     = (float*)d_out;
  mtp_attn_kernel<<<dim3(16384), dim3(64), 0, stream>>>(
      q, k_ctx, v_ctx, k_draft, v_draft, anchor, keep, out);
}

// Round 7
// 219.686 us; speedup vs baseline: 1.1458x; 1.1458x over previous
//
#include <hip/hip_runtime.h>

// Problem constants (fixed by setup_inputs)
constexpr int H_  = 32;
constexpr int N_  = 256;
constexpr int BS_ = 32;
constexpr int W_  = 128;
constexpr int T_  = 4096;
constexpr int D_  = 128;
constexpr int NQ_ = 8192;          // N_*BS_
constexpr float SCALE_  = 0.08838834764831845f;  // 1/sqrt(128)
constexpr float L2E_    = 1.4426950408889634f;
constexpr float MFLOOR_ = -1.0e28f;
constexpr float DEFER_  = 8.0f;                  // defer-max threshold (T13)

typedef __attribute__((ext_vector_type(4))) float f4;
typedef __attribute__((ext_vector_type(4))) short s4;
typedef __attribute__((ext_vector_type(8))) short s8;
typedef __attribute__((ext_vector_type(4))) float fx4;
typedef __attribute__((ext_vector_type(2))) int i2;

// one v_cvt_pk_bf16_f32: D.lo = bf16(a), D.hi = bf16(b)  (RNE)
__device__ __forceinline__ int pack2(float a, float b) {
  int r;
  asm("v_cvt_pk_bf16_f32 %0, %1, %2" : "=v"(r) : "v"(a), "v"(b));
  return r;
}

union frag_u { int w[4]; s8 v; };

// Workgroup barrier draining ONLY lgkmcnt; reg-dest global loads stay in flight.
__device__ __forceinline__ void lds_barrier() {
  asm volatile("s_waitcnt lgkmcnt(0)" ::: "memory");
  __builtin_amdgcn_s_barrier();
}

__global__ __launch_bounds__(128, 2)
void mtp_attn_kernel(const float* __restrict__ q,
                     const float* __restrict__ k_ctx,
                     const float* __restrict__ v_ctx,
                     const float* __restrict__ k_draft,
                     const float* __restrict__ v_draft,
                     const int* __restrict__ anchor,
                     const int* __restrict__ keepm,
                     float* __restrict__ out)
{
  // XCD-chunked swizzle (8192 % 8 == 0 -> bijective)
  int u = blockIdx.x;
  u = (u & 7) * 1024 + (u >> 3);
  const int h = u >> 8;
  const int n = u & 255;

  const int tu   = threadIdx.x;  // 0..127
  const int lane = tu & 63;
  const int wu   = tu >> 6;      // wave id: queries wu*16..+15
  const int l15  = lane & 15;
  const int g    = lane >> 4;    // 0..3
  const int rb   = tu >> 5;      // 0..3 (V staging row group)
  const int c4   = tu & 31;      // V staging float4 column

  const int A  = anchor[n];
  const int kp = keepm[n];
  const int wm = W_ - A;         // ctx key valid iff key >= wm

  // LDS: V^T double buffer, 2 x bf16 [128][36] = 2 x 9216 B
  __shared__ __align__(16) unsigned char smem_[18432];
  short* vT0 = (short*)smem_;
  short* vT1 = (short*)(smem_ + 9216);

  // ---- Q B-fragments (bf16 via cvt_pk), kept in registers ----
  const float* qrow = q + ((size_t)h * NQ_ + (size_t)n * BS_ + wu * 16 + l15) * D_;
  s8 qb[4];
#pragma unroll
  for (int ks = 0; ks < 4; ++ks) {
    f4 f0 = *reinterpret_cast<const f4*>(qrow + ks * 32 + g * 4);
    f4 f1 = *reinterpret_cast<const f4*>(qrow + ks * 32 + 16 + g * 4);
    frag_u uq;
    uq.w[0] = pack2(f0[0], f0[1]); uq.w[1] = pack2(f0[2], f0[3]);
    uq.w[2] = pack2(f1[0], f1[1]); uq.w[3] = pack2(f1[2], f1[3]);
    qb[ks] = uq.v;
  }

  // global source bases
  const float* kcb = k_ctx + (size_t)h * T_ * D_;
  const float* vcb = v_ctx + (size_t)h * T_ * D_;
  const float* kdb = k_draft + ((size_t)h * NQ_ + (size_t)n * BS_) * D_;
  const float* vdb = v_draft + ((size_t)h * NQ_ + (size_t)n * BS_) * D_;

  f4 vr[8];    // V chunk staging regs (1 chunk ahead of LDS write)
  f4 kf[16];   // K A-fragment regs for current chunk (direct from global)

  auto loadV = [&](int c) {
#pragma unroll
    for (int p = 0; p < 2; ++p)
#pragma unroll
      for (int i = 0; i < 4; ++i) {
        int row = p * 16 + rb * 4 + i;
        const float* src;
        if (c < 4) { int idx = A - W_ + c * 32 + row; idx = idx < 0 ? 0 : idx; src = vcb + (size_t)idx * D_; }
        else       { src = vdb + (size_t)row * D_; }
        vr[p * 4 + i] = reinterpret_cast<const f4*>(src)[c4];
      }
  };
  auto loadK = [&](int c) {      // lane reads rows l15 and 16+l15 of the chunk
    const float* s0; const float* s1;
    if (c < 4) {
      int i0 = A - W_ + c * 32 + l15;  int i1 = i0 + 16;
      i0 = i0 < 0 ? 0 : i0;            i1 = i1 < 0 ? 0 : i1;
      s0 = kcb + (size_t)i0 * D_;      s1 = kcb + (size_t)i1 * D_;
    } else {
      s0 = kdb + (size_t)l15 * D_;     s1 = s0 + 16 * D_;
    }
#pragma unroll
    for (int ks = 0; ks < 4; ++ks) {
      kf[ks * 2 + 0]     = reinterpret_cast<const f4*>(s0)[ks * 8 + g];
      kf[ks * 2 + 1]     = reinterpret_cast<const f4*>(s0)[ks * 8 + 4 + g];
      kf[8 + ks * 2 + 0] = reinterpret_cast<const f4*>(s1)[ks * 8 + g];
      kf[8 + ks * 2 + 1] = reinterpret_cast<const f4*>(s1)[ks * 8 + 4 + g];
    }
  };
  auto writeV = [&](short* buf) {  // cooperative 128-thread transpose store
#pragma unroll
    for (int p = 0; p < 2; ++p) {
      int keyl = p * 16 + rb * 4;
#pragma unroll
      for (int j = 0; j < 4; ++j) {
        i2 w = { pack2(vr[p * 4 + 0][j], vr[p * 4 + 1][j]),
                 pack2(vr[p * 4 + 2][j], vr[p * 4 + 3][j]) };
        *reinterpret_cast<i2*>(buf + (c4 * 4 + j) * 36 + keyl) = w;
      }
    }
  };

  // ---- prologue: V(0) -> buf0, V(1) -> regs, K(0) -> regs ----
  loadV(0);
  loadK(0);
  writeV(vT0);
  loadV(1);

  float m  = -3.0e38f;
  float ls = 0.0f;
  fx4 oacc[8];
#pragma unroll
  for (int t = 0; t < 8; ++t) oacc[t] = {0.f, 0.f, 0.f, 0.f};

  lds_barrier();   // V(0) visible to both waves

#pragma unroll
  for (int c = 0; c < 5; ++c) {
    // ---- stage V(c+1) into the other buffer; reissue vr for V(c+2) ----
    if (c < 4) writeV((c & 1) ? vT0 : vT1);
    if (c < 3) loadV(c + 2);

    // ---- QK^T swapped, K direct from global: st = mfma(K, Q) ----
    fx4 st[2] = { {0.f,0.f,0.f,0.f}, {0.f,0.f,0.f,0.f} };
    __builtin_amdgcn_s_setprio(1);
#pragma unroll
    for (int t2 = 0; t2 < 2; ++t2)
#pragma unroll
      for (int ks = 0; ks < 4; ++ks) {
        f4 f0 = kf[t2 * 8 + ks * 2 + 0];
        f4 f1 = kf[t2 * 8 + ks * 2 + 1];
        frag_u uk;
        uk.w[0] = pack2(f0[0], f0[1]); uk.w[1] = pack2(f0[2], f0[3]);
        uk.w[2] = pack2(f1[0], f1[1]); uk.w[3] = pack2(f1[2], f1[3]);
        st[t2] = __builtin_amdgcn_mfma_f32_16x16x32_bf16(uk.v, qb[ks], st[t2], 0, 0, 0);
      }
    __builtin_amdgcn_s_setprio(0);
    if (c < 4) loadK(c + 1);     // kf free after conversion; full chunk to land

    // ---- mask + scale + chunk max (per query q = l15) ----
    float sv[2][4];
    float cm = -3.0e38f;
#pragma unroll
    for (int t2 = 0; t2 < 2; ++t2) {
      int kb0 = c * 32 + t2 * 16 + g * 4;
#pragma unroll
      for (int r = 0; r < 4; ++r) {
        float v = st[t2][r] * SCALE_;
        bool valid = (c == 4) || (kb0 + r >= wm);
        v = valid ? v : -1.0e30f;
        sv[t2][r] = v;
        cm = fmaxf(cm, v);
      }
    }
    cm = fmaxf(cm, __shfl_xor(cm, 16));
    cm = fmaxf(cm, __shfl_xor(cm, 32));

    // ---- online max with defer threshold ----
    if (c == 0) {
      m = fmaxf(cm, MFLOOR_);
    } else {
      float pm = fmaxf(m, cm);
      if (!__all(pm - m <= DEFER_)) {
        float mn = fmaxf(pm, MFLOOR_);
        float al = exp2f((m - mn) * L2E_);
        ls *= al;
        float alr[4];
#pragma unroll
        for (int r = 0; r < 4; ++r) alr[r] = __shfl(al, g * 4 + r);
#pragma unroll
        for (int nt = 0; nt < 8; ++nt)
#pragma unroll
          for (int r = 0; r < 4; ++r) oacc[nt][r] *= alr[r];
        m = mn;
      }
    }

    // ---- p = exp, accumulate l, pack PV A-fragment (lane-local) ----
    float pv[8];
#pragma unroll
    for (int t2 = 0; t2 < 2; ++t2)
#pragma unroll
      for (int r = 0; r < 4; ++r) {
        float p = exp2f((sv[t2][r] - m) * L2E_);
        ls += p;
        pv[t2 * 4 + r] = p;
      }
    frag_u up;
    up.w[0] = pack2(pv[0], pv[1]); up.w[1] = pack2(pv[2], pv[3]);
    up.w[2] = pack2(pv[4], pv[5]); up.w[3] = pack2(pv[6], pv[7]);
    s8 pa = up.v;

    // ---- PV: O[q][d] += P * V (reads buf[c%2]) ----
    const short* vb = (c & 1) ? vT1 : vT0;
    __builtin_amdgcn_s_setprio(1);
#pragma unroll
    for (int nt = 0; nt < 8; ++nt) {
      const short* vp = vb + (nt * 16 + l15) * 36 + g * 4;
      s4 b0 = *reinterpret_cast<const s4*>(vp);
      s4 b1 = *reinterpret_cast<const s4*>(vp + 16);
      s8 vb2 = { b0[0], b0[1], b0[2], b0[3], b1[0], b1[1], b1[2], b1[3] };
      oacc[nt] = __builtin_amdgcn_mfma_f32_16x16x32_bf16(pa, vb2, oacc[nt], 0, 0, 0);
    }
    __builtin_amdgcn_s_setprio(0);

    // ---- single barrier per chunk: my V(c+1) writes visible; everyone done
    //      reading buf[c%2] before chunk c+1 overwrites it ----
    if (c < 4) lds_barrier();
  }

  // ---- epilogue: reduce l across key-groups, redistribute, normalize, store ----
  ls += __shfl_xor(ls, 16);
  ls += __shfl_xor(ls, 32);
  float linv[4];
#pragma unroll
  for (int r = 0; r < 4; ++r) {
    float lq = __shfl(ls, g * 4 + r);
    linv[r] = kp ? (1.0f / lq) : 0.0f;
  }
  float* ob = out + ((size_t)h * NQ_ + (size_t)n * BS_ + wu * 16 + g * 4) * D_ + l15;
#pragma unroll
  for (int nt = 0; nt < 8; ++nt)
#pragma unroll
    for (int r = 0; r < 4; ++r)
      ob[(size_t)r * D_ + nt * 16] = oacc[nt][r] * linv[r];
}

extern "C" void kernel_launch(void* const* d_in, const int* in_sizes, int n_in,
                              void* d_out, int out_size, void* d_ws, size_t ws_size,
                              hipStream_t stream) {
  (void)in_sizes; (void)n_in; (void)d_ws; (void)ws_size; (void)out_size;
  const float* q       = (const float*)d_in[0];
  const float* k_ctx   = (const float*)d_in[1];
  const float* v_ctx   = (const float*)d_in[2];
  const float* k_draft = (const float*)d_in[3];
  const float* v_draft = (const float*)d_in[4];
  const int*   anchor  = (const int*)d_in[5];
  const int*   keep    = (const int*)d_in[6];
  float*       out     = (float*)d_out;
  mtp_attn_kernel<<<dim3(8192), dim3(128), 0, stream>>>(
      q, k_ctx, v_ctx, k_draft, v_draft, anchor, keep, out);
}

// Round 9
// 152.649 us; speedup vs baseline: 1.6490x; 1.4392x over previous
//
#include <hip/hip_runtime.h>

// Problem constants (fixed by setup_inputs)
constexpr int H_  = 32;
constexpr int N_  = 256;
constexpr int BS_ = 32;
constexpr int W_  = 128;
constexpr int T_  = 4096;
constexpr int D_  = 128;
constexpr int NQ_ = 8192;          // N_*BS_
constexpr float SCALE_  = 0.08838834764831845f;  // 1/sqrt(128)
constexpr float L2E_    = 1.4426950408889634f;
constexpr float MFLOOR_ = -1.0e28f;
constexpr float DEFER_  = 8.0f;                  // defer-max threshold (T13)

typedef __attribute__((ext_vector_type(4))) float f4;
typedef __attribute__((ext_vector_type(4))) short s4;
typedef __attribute__((ext_vector_type(8))) short s8;
typedef __attribute__((ext_vector_type(4))) float fx4;
typedef __attribute__((ext_vector_type(2))) int i2;

// one v_cvt_pk_bf16_f32: D.lo = bf16(a), D.hi = bf16(b)  (RNE)
__device__ __forceinline__ int pack2(float a, float b) {
  int r;
  asm("v_cvt_pk_bf16_f32 %0, %1, %2" : "=v"(r) : "v"(a), "v"(b));
  return r;
}

union frag_u { int w[4]; s8 v; };

// Workgroup barrier draining ONLY lgkmcnt; reg-dest global loads stay in flight.
__device__ __forceinline__ void lds_barrier() {
  asm volatile("s_waitcnt lgkmcnt(0)" ::: "memory");
  __builtin_amdgcn_s_barrier();
}

__global__ __launch_bounds__(128, 2)
void mtp_attn_kernel(const float* __restrict__ q,
                     const float* __restrict__ k_ctx,
                     const float* __restrict__ v_ctx,
                     const float* __restrict__ k_draft,
                     const float* __restrict__ v_draft,
                     const int* __restrict__ anchor,
                     const int* __restrict__ keepm,
                     float* __restrict__ out)
{
  // XCD-chunked swizzle (8192 % 8 == 0 -> bijective)
  int u = blockIdx.x;
  u = (u & 7) * 1024 + (u >> 3);
  const int h = u >> 8;
  const int n = u & 255;

  const int tu   = threadIdx.x;  // 0..127
  const int lane = tu & 63;
  const int wu   = tu >> 6;      // wave id: queries wu*16..+15
  const int l15  = lane & 15;
  const int g    = lane >> 4;    // 0..3
  const int rb   = tu >> 5;      // 0..3 (V staging row group)
  const int c4   = tu & 31;      // staging float4 column

  const int A  = anchor[n];
  const int kp = keepm[n];
  const int wm = W_ - A;         // ctx key valid iff key >= wm

  // LDS double buffers: K [2][32][132] bf16 (2x8448B) + V^T [2][128][36] bf16 (2x9216B)
  __shared__ __align__(16) unsigned char smem_[35328];
  short* Kb[2] = { (short*)smem_,          (short*)(smem_ + 8448) };
  short* Vb[2] = { (short*)(smem_ + 16896), (short*)(smem_ + 16896 + 9216) };

  // ---- Q B-fragments (bf16 via cvt_pk), kept in registers ----
  const float* qrow = q + ((size_t)h * NQ_ + (size_t)n * BS_ + wu * 16 + l15) * D_;
  s8 qb[4];
#pragma unroll
  for (int ks = 0; ks < 4; ++ks) {
    f4 f0 = *reinterpret_cast<const f4*>(qrow + ks * 32 + g * 4);
    f4 f1 = *reinterpret_cast<const f4*>(qrow + ks * 32 + 16 + g * 4);
    frag_u uq;
    uq.w[0] = pack2(f0[0], f0[1]); uq.w[1] = pack2(f0[2], f0[3]);
    uq.w[2] = pack2(f1[0], f1[1]); uq.w[3] = pack2(f1[2], f1[3]);
    qb[ks] = uq.v;
  }

  // global source bases
  const float* kcb = k_ctx + (size_t)h * T_ * D_;
  const float* vcb = v_ctx + (size_t)h * T_ * D_;
  const float* kdb = k_draft + ((size_t)h * NQ_ + (size_t)n * BS_) * D_;
  const float* vdb = v_draft + ((size_t)h * NQ_ + (size_t)n * BS_) * D_;

  // ---- staging: explicit depth-2 register sets (set x holds chunk with parity x) ----
  f4 krA[8], vrA[8], krB[8], vrB[8];

  auto loadK = [&](f4 (&dst)[8], int c) {   // flat-contiguous: 2KB/instr coalesced
    if (c < 4) {
      int base = (A - W_ + c * 32) * 32;    // f4 units
      const f4* kc4 = reinterpret_cast<const f4*>(kcb);
#pragma unroll
      for (int i = 0; i < 8; ++i) {
        int off = base + tu + 128 * i;
        off = off < 0 ? 0 : off;            // clamped rows are masked later
        dst[i] = kc4[off];
      }
    } else {
      const f4* kd4 = reinterpret_cast<const f4*>(kdb);
#pragma unroll
      for (int i = 0; i < 8; ++i) dst[i] = kd4[tu + 128 * i];
    }
  };
  auto loadV = [&](f4 (&dst)[8], int c) {
#pragma unroll
    for (int p = 0; p < 2; ++p)
#pragma unroll
      for (int i = 0; i < 4; ++i) {
        int row = p * 16 + rb * 4 + i;
        const float* src;
        if (c < 4) { int idx = A - W_ + c * 32 + row; idx = idx < 0 ? 0 : idx; src = vcb + (size_t)idx * D_; }
        else       { src = vdb + (size_t)row * D_; }
        dst[p * 4 + i] = reinterpret_cast<const f4*>(src)[c4];
      }
  };
  auto writeK = [&](f4 (&src)[8], short* kb) {
#pragma unroll
    for (int i = 0; i < 8; ++i) {
      int row = (tu >> 5) + 4 * i;          // matches flat-load lane->row mapping
      i2 w = { pack2(src[i][0], src[i][1]), pack2(src[i][2], src[i][3]) };
      *reinterpret_cast<i2*>(kb + row * 132 + c4 * 4) = w;
    }
  };
  auto writeV = [&](f4 (&src)[8], short* vT) {  // 4x4 transpose -> vT[d][key]
#pragma unroll
    for (int p = 0; p < 2; ++p) {
      int keyl = p * 16 + rb * 4;
#pragma unroll
      for (int j = 0; j < 4; ++j) {
        i2 w = { pack2(src[p * 4 + 0][j], src[p * 4 + 1][j]),
                 pack2(src[p * 4 + 2][j], src[p * 4 + 3][j]) };
        *reinterpret_cast<i2*>(vT + (c4 * 4 + j) * 36 + keyl) = w;
      }
    }
  };

  // ---- prologue: chunk0 -> buf0 via set A; preload chunk1 (S1) and chunk2 (S0) ----
  loadK(krA, 0); loadV(vrA, 0);
  loadK(krB, 1); loadV(vrB, 1);
  writeK(krA, Kb[0]); writeV(vrA, Vb[0]);
  loadK(krA, 2); loadV(vrA, 2);

  float m  = -3.0e38f;
  float ls = 0.0f;
  fx4 oacc[8];
#pragma unroll
  for (int t = 0; t < 8; ++t) oacc[t] = {0.f, 0.f, 0.f, 0.f};

  lds_barrier();   // chunk0 visible to both waves

#pragma unroll
  for (int c = 0; c < 5; ++c) {
    // ---- stage chunk c+1 (set parity (c+1)&1) into buf (c+1)&1; reload set for c+3 ----
    if (c < 4) {
      f4 (&kw)[8] = ((c + 1) & 1) ? krB : krA;
      f4 (&vw)[8] = ((c + 1) & 1) ? vrB : vrA;
      writeK(kw, Kb[(c + 1) & 1]);
      writeV(vw, Vb[(c + 1) & 1]);
      if (c < 3) { loadK(kw, c + 3); loadV(vw, c + 3); }
    }

    // ---- QK^T swapped: st = mfma(K, Q) -> lane holds S^T[key][q=l15] ----
    const short* kb = Kb[c & 1];
    fx4 st[2] = { {0.f,0.f,0.f,0.f}, {0.f,0.f,0.f,0.f} };
    __builtin_amdgcn_s_setprio(1);
#pragma unroll
    for (int ks = 0; ks < 4; ++ks) {
#pragma unroll
      for (int t2 = 0; t2 < 2; ++t2) {
        const short* kpr = kb + (t2 * 16 + l15) * 132 + ks * 32 + g * 4;
        s4 b0 = *reinterpret_cast<const s4*>(kpr);
        s4 b1 = *reinterpret_cast<const s4*>(kpr + 16);
        s8 kf = { b0[0], b0[1], b0[2], b0[3], b1[0], b1[1], b1[2], b1[3] };
        st[t2] = __builtin_amdgcn_mfma_f32_16x16x32_bf16(kf, qb[ks], st[t2], 0, 0, 0);
      }
    }
    __builtin_amdgcn_s_setprio(0);

    // ---- mask + scale + chunk max (per query q = l15) ----
    float sv[2][4];
    float cm = -3.0e38f;
#pragma unroll
    for (int t2 = 0; t2 < 2; ++t2) {
      int kb0 = c * 32 + t2 * 16 + g * 4;
#pragma unroll
      for (int r = 0; r < 4; ++r) {
        float v = st[t2][r] * SCALE_;
        bool valid = (c == 4) || (kb0 + r >= wm);
        v = valid ? v : -1.0e30f;
        sv[t2][r] = v;
        cm = fmaxf(cm, v);
      }
    }
    cm = fmaxf(cm, __shfl_xor(cm, 16));
    cm = fmaxf(cm, __shfl_xor(cm, 32));

    // ---- online max with defer threshold ----
    if (c == 0) {
      m = fmaxf(cm, MFLOOR_);
    } else {
      float pm = fmaxf(m, cm);
      if (!__all(pm - m <= DEFER_)) {
        float mn = fmaxf(pm, MFLOOR_);
        float al = exp2f((m - mn) * L2E_);
        ls *= al;
        float alr[4];
#pragma unroll
        for (int r = 0; r < 4; ++r) alr[r] = __shfl(al, g * 4 + r);
#pragma unroll
        for (int nt = 0; nt < 8; ++nt)
#pragma unroll
          for (int r = 0; r < 4; ++r) oacc[nt][r] *= alr[r];
        m = mn;
      }
    }

    // ---- p = exp, accumulate l, pack PV A-fragment (lane-local) ----
    float pv[8];
#pragma unroll
    for (int t2 = 0; t2 < 2; ++t2)
#pragma unroll
      for (int r = 0; r < 4; ++r) {
        float p = exp2f((sv[t2][r] - m) * L2E_);
        ls += p;
        pv[t2 * 4 + r] = p;
      }
    frag_u up;
    up.w[0] = pack2(pv[0], pv[1]); up.w[1] = pack2(pv[2], pv[3]);
    up.w[2] = pack2(pv[4], pv[5]); up.w[3] = pack2(pv[6], pv[7]);
    s8 pa = up.v;

    // ---- PV: O[q][d] += P * V (reads Vb[c&1]) ----
    const short* vT = Vb[c & 1];
    __builtin_amdgcn_s_setprio(1);
#pragma unroll
    for (int nt = 0; nt < 8; ++nt) {
      const short* vp = vT + (nt * 16 + l15) * 36 + g * 4;
      s4 b0 = *reinterpret_cast<const s4*>(vp);
      s4 b1 = *reinterpret_cast<const s4*>(vp + 16);
      s8 vb2 = { b0[0], b0[1], b0[2], b0[3], b1[0], b1[1], b1[2], b1[3] };
      oacc[nt] = __builtin_amdgcn_mfma_f32_16x16x32_bf16(pa, vb2, oacc[nt], 0, 0, 0);
    }
    __builtin_amdgcn_s_setprio(0);

    // ---- single barrier per chunk: writes of c+1 visible; all reads of buf[c&1]
    //      done before iter c+1 overwrites buf[(c+2)&1] == buf[c&1] ----
    if (c < 4) lds_barrier();
  }

  // ---- epilogue: reduce l across key-groups, redistribute, normalize, store ----
  ls += __shfl_xor(ls, 16);
  ls += __shfl_xor(ls, 32);
  float linv[4];
#pragma unroll
  for (int r = 0; r < 4; ++r) {
    float lq = __shfl(ls, g * 4 + r);
    linv[r] = kp ? (1.0f / lq) : 0.0f;
  }
  float* ob = out + ((size_t)h * NQ_ + (size_t)n * BS_ + wu * 16 + g * 4) * D_ + l15;
#pragma unroll
  for (int nt = 0; nt < 8; ++nt)
#pragma unroll
    for (int r = 0; r < 4; ++r)
      ob[(size_t)r * D_ + nt * 16] = oacc[nt][r] * linv[r];
}

extern "C" void kernel_launch(void* const* d_in, const int* in_sizes, int n_in,
                              void* d_out, int out_size, void* d_ws, size_t ws_size,
                              hipStream_t stream) {
  (void)in_sizes; (void)n_in; (void)d_ws; (void)ws_size; (void)out_size;
  const float* q       = (const float*)d_in[0];
  const float* k_ctx   = (const float*)d_in[1];
  const float* v_ctx   = (const float*)d_in[2];
  const float* k_draft = (const float*)d_in[3];
  const float* v_draft = (const float*)d_in[4];
  const int*   anchor  = (const int*)d_in[5];
  const int*   keep    = (const int*)d_in[6];
  float*       out     = (float*)d_out;
  mtp_attn_kernel<<<dim3(8192), dim3(128), 0, stream>>>(
      q, k_ctx, v_ctx, k_draft, v_draft, anchor, keep, out);
}